// Round 15
// baseline (1209.150 us; speedup 1.0000x reference)
//
#include <hip/hip_runtime.h>
#include <hip/hip_bf16.h>

// Problem constants: B=4, N=2048, DIM=512, H=8, DH=64, ORDER=3, TOPK=64, INNER=512
#define SLOTS 80   // sparse slots per row (64 + tie headroom)

typedef __bf16 bf16x8 __attribute__((ext_vector_type(8)));
typedef float  f32x4  __attribute__((ext_vector_type(4)));

// ---------------------------------------------------------------------------
// K1/K4: fp32 tiled GEMM with bias (unchanged).
// ---------------------------------------------------------------------------
__global__ __launch_bounds__(256)
void sgemm_bias(const float* __restrict__ A, const float* __restrict__ Bm,
                const float* __restrict__ bias, float* __restrict__ C,
                int M, int N, int K)
{
    __shared__ float As[16][132];
    __shared__ float Bs[16][132];

    const int t  = threadIdx.x;
    const int tx = t & 15, ty = t >> 4;
    const int bm = blockIdx.y << 7, bn = blockIdx.x << 7;

    const int arow = t >> 2,  ak4 = (t & 3) << 2;
    const int bkr  = t >> 5,  bc4 = (t & 31) << 2;

    float4 pa[2], pb[2];
#pragma unroll
    for (int s = 0; s < 2; ++s) {
        pa[s] = *(const float4*)&A[(size_t)(bm + arow + (s << 6)) * K + ak4];
        pb[s] = *(const float4*)&Bm[(size_t)(bkr + (s << 3)) * N + bn + bc4];
    }

    float acc[8][8] = {};

    for (int k0 = 0; k0 < K; k0 += 16) {
        __syncthreads();
#pragma unroll
        for (int s = 0; s < 2; ++s) {
            const int ar = arow + (s << 6);
            As[ak4 + 0][ar] = pa[s].x;
            As[ak4 + 1][ar] = pa[s].y;
            As[ak4 + 2][ar] = pa[s].z;
            As[ak4 + 3][ar] = pa[s].w;
            *(float4*)&Bs[bkr + (s << 3)][bc4] = pb[s];
        }
        __syncthreads();
        if (k0 + 16 < K) {
#pragma unroll
            for (int s = 0; s < 2; ++s) {
                pa[s] = *(const float4*)&A[(size_t)(bm + arow + (s << 6)) * K + k0 + 16 + ak4];
                pb[s] = *(const float4*)&Bm[(size_t)(k0 + 16 + bkr + (s << 3)) * N + bn + bc4];
            }
        }
#pragma unroll
        for (int kk = 0; kk < 16; ++kk) {
            float4 a0 = *(const float4*)&As[kk][(ty << 3) + 0];
            float4 a1 = *(const float4*)&As[kk][(ty << 3) + 4];
            float4 b0 = *(const float4*)&Bs[kk][(tx << 2)];
            float4 b1 = *(const float4*)&Bs[kk][64 + (tx << 2)];
            float ar[8] = {a0.x, a0.y, a0.z, a0.w, a1.x, a1.y, a1.z, a1.w};
            float br[8] = {b0.x, b0.y, b0.z, b0.w, b1.x, b1.y, b1.z, b1.w};
#pragma unroll
            for (int i = 0; i < 8; ++i)
#pragma unroll
                for (int j = 0; j < 8; ++j)
                    acc[i][j] = fmaf(ar[i], br[j], acc[i][j]);
        }
    }

    float bb[8];
#pragma unroll
    for (int j = 0; j < 4; ++j) {
        bb[j]     = bias[bn + (tx << 2) + j];
        bb[j + 4] = bias[bn + 64 + (tx << 2) + j];
    }
#pragma unroll
    for (int i = 0; i < 8; ++i) {
        const size_t row = (size_t)(bm + (ty << 3) + i);
        float4 o0 = {acc[i][0] + bb[0], acc[i][1] + bb[1], acc[i][2] + bb[2], acc[i][3] + bb[3]};
        float4 o1 = {acc[i][4] + bb[4], acc[i][5] + bb[5], acc[i][6] + bb[6], acc[i][7] + bb[7]};
        *(float4*)&C[row * N + bn + (tx << 2)]      = o0;
        *(float4*)&C[row * N + bn + 64 + (tx << 2)] = o1;
    }
}

// ---------------------------------------------------------------------------
// K1b: exact bf16x3 split of Q and K into packed [bh][row][192] planes
// ([0:64]=hi, [64:128]=mid, [128:192]=lo). x == hi+mid+lo exactly (24-bit
// mantissa covered by 3x8). One thread per (b,n,h,d).
// ---------------------------------------------------------------------------
__global__ __launch_bounds__(256)
void qk_split(const float* __restrict__ qkv, unsigned short* __restrict__ qcat,
              unsigned short* __restrict__ kcat)
{
    const int gid = blockIdx.x * 256 + threadIdx.x;   // 0 .. 4194303
    const int d = gid & 63;
    const int h = (gid >> 6) & 7;
    const int n = (gid >> 9) & 2047;
    const int b = gid >> 20;

    const size_t src = ((size_t)(b * 2048 + n)) * 1536 + (h << 6) + d;
    const size_t dst = ((size_t)((b << 3) + h) * 2048 + n) * 192 + d;

#pragma unroll
    for (int qk = 0; qk < 2; ++qk) {
        const float x = qkv[src + (qk ? 512 : 0)];
        unsigned short* out = qk ? kcat : qcat;
        __hip_bfloat16 h0 = __float2bfloat16(x);
        const float f0 = __bfloat162float(h0);
        const float r1 = x - f0;
        __hip_bfloat16 h1 = __float2bfloat16(r1);
        const float f1 = __bfloat162float(h1);
        const float r2 = r1 - f1;
        __hip_bfloat16 h2 = __float2bfloat16(r2);
        out[dst]       = *(unsigned short*)&h0;
        out[dst + 64]  = *(unsigned short*)&h1;
        out[dst + 128] = *(unsigned short*)&h2;
    }
}

// ---------------------------------------------------------------------------
// K2 v15: MFMA QK^T. Block = 512 thr (8 waves) owns 16 rows of one (b,h).
// A-fragments (Q rows, 6 x bf16x8: {hi,mid,lo} x 2 k-steps) held in regs.
// Per col-tile (16 cols): 6 B-fragment 16B loads (each wave-load covers 16
// full cache lines) + 12 mfma_f32_16x16x32_bf16 (pairs hi.hi, hi.mid,
// mid.hi, mid.mid, hi.lo, lo.hi — dropped terms <= 2^-26). C layout
// (m89-verified): col = lane&15, row = (lane>>4)*4 + reg.
// Scores -> S[16][2048] (128 KB) -> phase B (R14's early-exit bisection),
// 2 rows/wave.
// ---------------------------------------------------------------------------
__global__ __launch_bounds__(512, 2)
void scores_topk(const unsigned short* __restrict__ qcat,
                 const unsigned short* __restrict__ kcat,
                 float* __restrict__ svals,
                 unsigned short* __restrict__ sidx, int* __restrict__ scnt)
{
    __shared__ float S[16][2048];   // 128 KiB

    const int t    = threadIdx.x;
    const int lane = t & 63;
    const int wid  = t >> 6;                        // 0..7
    const int id   = blockIdx.x;                    // 0..4095
    const int bh   = ((id >> 10) << 3) | (id & 7);  // XCD-affine, bijective
    const int rowblk = (id >> 3) & 127;
    const int r0   = rowblk << 4;                   // block's 16 rows

    // A-fragments: lane supplies row r0+(lane&15), k-chunk (lane>>4)*8
    const size_t qbase =
        ((size_t)bh * 2048 + r0 + (lane & 15)) * 192 + ((lane >> 4) << 3);
    bf16x8 afr[6];
#pragma unroll
    for (int j = 0; j < 6; ++j)
        afr[j] = *(const bf16x8*)(qcat + qbase + j * 32);

    const size_t kbase =
        ((size_t)bh * 2048 + (lane & 15)) * 192 + ((lane >> 4) << 3);

#pragma unroll 1
    for (int i = 0; i < 16; ++i) {
        const int ct = (i << 3) + wid;              // wave's col-tile
        const size_t cb = kbase + (size_t)(ct << 4) * 192;
        bf16x8 b0 = *(const bf16x8*)(kcat + cb +   0);   // hi  ks0
        bf16x8 b1 = *(const bf16x8*)(kcat + cb +  32);   // hi  ks1
        bf16x8 b2 = *(const bf16x8*)(kcat + cb +  64);   // mid ks0
        bf16x8 b3 = *(const bf16x8*)(kcat + cb +  96);   // mid ks1
        bf16x8 b4 = *(const bf16x8*)(kcat + cb + 128);   // lo  ks0
        bf16x8 b5 = *(const bf16x8*)(kcat + cb + 160);   // lo  ks1

        f32x4 acc = {0.f, 0.f, 0.f, 0.f};
        acc = __builtin_amdgcn_mfma_f32_16x16x32_bf16(afr[0], b0, acc, 0, 0, 0); // hi.hi
        acc = __builtin_amdgcn_mfma_f32_16x16x32_bf16(afr[1], b1, acc, 0, 0, 0);
        acc = __builtin_amdgcn_mfma_f32_16x16x32_bf16(afr[0], b2, acc, 0, 0, 0); // hi.mid
        acc = __builtin_amdgcn_mfma_f32_16x16x32_bf16(afr[1], b3, acc, 0, 0, 0);
        acc = __builtin_amdgcn_mfma_f32_16x16x32_bf16(afr[2], b0, acc, 0, 0, 0); // mid.hi
        acc = __builtin_amdgcn_mfma_f32_16x16x32_bf16(afr[3], b1, acc, 0, 0, 0);
        acc = __builtin_amdgcn_mfma_f32_16x16x32_bf16(afr[2], b2, acc, 0, 0, 0); // mid.mid
        acc = __builtin_amdgcn_mfma_f32_16x16x32_bf16(afr[3], b3, acc, 0, 0, 0);
        acc = __builtin_amdgcn_mfma_f32_16x16x32_bf16(afr[0], b4, acc, 0, 0, 0); // hi.lo
        acc = __builtin_amdgcn_mfma_f32_16x16x32_bf16(afr[1], b5, acc, 0, 0, 0);
        acc = __builtin_amdgcn_mfma_f32_16x16x32_bf16(afr[4], b0, acc, 0, 0, 0); // lo.hi
        acc = __builtin_amdgcn_mfma_f32_16x16x32_bf16(afr[5], b1, acc, 0, 0, 0);

        const int col   = (ct << 4) + (lane & 15);
        const int rbase = (lane >> 4) << 2;
#pragma unroll
        for (int reg = 0; reg < 4; ++reg)
            S[rbase + reg][col] = acc[reg] * 0.125f;
    }
    __syncthreads();

    // phase B: 2 rows/wave; exact 64th-largest via early-exit bisection
    const unsigned long long pre64 = (1ull << lane) - 1ull;

#define PHASEB(RQ)                                                             \
    {                                                                          \
        const int rr = (wid << 1) + (RQ);                                      \
        float    fv[32];                                                       \
        unsigned uv[32];                                                       \
        _Pragma("unroll")                                                      \
        for (int m = 0; m < 32; ++m) {                                         \
            const float x = S[rr][lane + (m << 6)];                            \
            fv[m] = x;                                                         \
            const unsigned bx = __float_as_uint(x);                            \
            uv[m] = bx ^ (unsigned)(((int)bx >> 31) | 0x80000000);             \
        }                                                                      \
        unsigned lo = 0;                                                       \
        _Pragma("unroll 1")                                                    \
        for (int bit = 31; bit >= 0; --bit) {                                  \
            const unsigned mid = lo | (1u << bit);                             \
            int c = 0;                                                         \
            _Pragma("unroll")                                                  \
            for (int m = 0; m < 32; ++m)                                       \
                c += __popcll(__ballot(uv[m] >= mid));                         \
            if (c >= 64) {                                                     \
                lo = mid;                                                      \
                if (c == 64) break;                                            \
            }                                                                  \
        }                                                                      \
        unsigned um = 0;                                                       \
        _Pragma("unroll")                                                      \
        for (int m = 0; m < 32; ++m) um = uv[m] > um ? uv[m] : um;             \
        _Pragma("unroll")                                                      \
        for (int off = 1; off < 64; off <<= 1) {                               \
            const unsigned o = (unsigned)__shfl_xor((int)um, off, 64);         \
            um = o > um ? o : um;                                              \
        }                                                                      \
        const unsigned mbm = (um & 0x80000000u) ? (um ^ 0x80000000u) : ~um;    \
        const float Mx = __uint_as_float(mbm);                                 \
        float zs = 0.f;                                                        \
        _Pragma("unroll")                                                      \
        for (int m = 0; m < 32; ++m) {                                         \
            const bool keep = uv[m] >= lo;                                     \
            const float ex = keep ? __expf(fv[m] - Mx) : 0.f;                  \
            fv[m] = ex;                                                        \
            zs += ex;                                                          \
        }                                                                      \
        _Pragma("unroll")                                                      \
        for (int off = 1; off < 64; off <<= 1) zs += __shfl_xor(zs, off, 64);  \
        const float zinv = 1.0f / zs;                                          \
        const size_t grow = (size_t)bh * 2048 + r0 + rr;                       \
        float* vd           = svals + grow * SLOTS;                            \
        unsigned short* idp = sidx  + grow * SLOTS;                            \
        int base = 0;                                                          \
        _Pragma("unroll")                                                      \
        for (int m = 0; m < 32; ++m) {                                         \
            const bool keep = uv[m] >= lo;                                     \
            unsigned long long ball = __ballot(keep);                          \
            if (keep) {                                                        \
                const int my = base + __popcll(ball & pre64);                  \
                if (my < SLOTS) {                                              \
                    vd[my]  = fv[m] * zinv;                                    \
                    idp[my] = (unsigned short)(lane + (m << 6));               \
                }                                                              \
            }                                                                  \
            base += __popcll(ball);                                            \
        }                                                                      \
        if (lane == 0) scnt[grow] = base < SLOTS ? base : SLOTS;               \
    }

    PHASEB(0)
    PHASEB(1)
#undef PHASEB
}

// ---------------------------------------------------------------------------
// K3: sparse attn application (unchanged from R14: x8 unroll + XCD-affine).
// ---------------------------------------------------------------------------
__global__ __launch_bounds__(256)
void spmm(const float* __restrict__ svals, const unsigned short* __restrict__ sidx,
          const int* __restrict__ scnt, const float* __restrict__ qkv,
          const float* __restrict__ vin, float* __restrict__ vout,
          float* __restrict__ res, const float* __restrict__ alphas_raw, int order)
{
    const int lane = threadIdx.x & 63;
    const int id   = blockIdx.x;                      // 0..16383
    const int bh   = ((id & 7) << 2) | (id >> 12);    // XCD-affine, bijective
    const int nblk = (id >> 3) & 511;
    const int n    = (nblk << 2) + (threadIdx.x >> 6);
    const int gr   = (bh << 11) + n;
    const int b    = bh >> 3,  h = bh & 7;

    const float* vb;
    int stride;
    if (order == 0) { vb = qkv + (size_t)b * 2048 * 1536 + 1024 + (h << 6); stride = 1536; }
    else            { vb = vin + ((size_t)bh << 17);                        stride = 64;   }

    const int cnt = scnt[gr];
    const float* va          = svals + (size_t)gr * SLOTS;
    const unsigned short* ia = sidx  + (size_t)gr * SLOTS;

    float acc = 0.f;
    int j = 0;
    for (; j + 8 <= cnt; j += 8) {
        float a0 = va[j],     a1 = va[j + 1], a2 = va[j + 2], a3 = va[j + 3];
        float a4 = va[j + 4], a5 = va[j + 5], a6 = va[j + 6], a7 = va[j + 7];
        int   i0 = ia[j],     i1 = ia[j + 1], i2 = ia[j + 2], i3 = ia[j + 3];
        int   i4 = ia[j + 4], i5 = ia[j + 5], i6 = ia[j + 6], i7 = ia[j + 7];
        acc += a0 * vb[(size_t)i0 * stride + lane];
        acc += a1 * vb[(size_t)i1 * stride + lane];
        acc += a2 * vb[(size_t)i2 * stride + lane];
        acc += a3 * vb[(size_t)i3 * stride + lane];
        acc += a4 * vb[(size_t)i4 * stride + lane];
        acc += a5 * vb[(size_t)i5 * stride + lane];
        acc += a6 * vb[(size_t)i6 * stride + lane];
        acc += a7 * vb[(size_t)i7 * stride + lane];
    }
    for (; j < cnt; ++j) acc += va[j] * vb[(size_t)ia[j] * stride + lane];

    if (order < 2) vout[((size_t)gr << 6) + lane] = acc;

    float ar    = alphas_raw[(order << 3) + h];
    float alpha = ar * 0.5f * (1.0f + erff(ar * 0.70710678f));  // exact gelu
    size_t ro = ((size_t)b * 2048 + n) * 512 + (h << 6) + lane;
    float av  = alpha * acc;
    if (order == 0) res[ro] = av;
    else            res[ro] += av;
}

// ---------------------------------------------------------------------------
extern "C" void kernel_launch(void* const* d_in, const int* in_sizes, int n_in,
                              void* d_out, int out_size, void* d_ws, size_t ws_size,
                              hipStream_t stream)
{
    const float* x      = (const float*)d_in[0];
    const float* Wqkv   = (const float*)d_in[1];
    const float* bqkv   = (const float*)d_in[2];
    const float* Wout   = (const float*)d_in[3];
    const float* bout   = (const float*)d_in[4];
    const float* alphas = (const float*)d_in[5];
    float* out = (float*)d_out;

    // workspace layout (bytes)
    char* ws = (char*)d_ws;
    float*          qkvb  = (float*)ws;                       // 50331648
    float*          svals = (float*)(ws + 50331648);          // 20971520
    unsigned short* sidxp = (unsigned short*)(ws + 71303168); // 10485760
    int*            scntp = (int*)(ws + 81788928);            // 262144
    // v1/v2/resb region (50331648 B at +82051072) is time-shared:
    //  - during K1b/K2: qcat (25165824) + kcat (25165824)
    //  - during spmm/K4: v1, v2, resb (3 x 16777216)
    unsigned short* qcat  = (unsigned short*)(ws + 82051072);
    unsigned short* kcat  = (unsigned short*)(ws + 107216896);
    float*          v1    = (float*)(ws + 82051072);
    float*          v2    = (float*)(ws + 98828288);
    float*          resb  = (float*)(ws + 115605504);
    if (ws_size < 132382720) return;                          // need ~126 MB

    // K1: qkv = x @ Wqkv + bqkv
    sgemm_bias<<<dim3(1536 / 128, 8192 / 128), 256, 0, stream>>>(
        x, Wqkv, bqkv, qkvb, 8192, 1536, 512);

    // K1b: exact bf16x3 split of Q,K
    qk_split<<<16384, 256, 0, stream>>>(qkvb, qcat, kcat);

    // K2: MFMA scores -> exact top-64(+ties) -> softmax -> sparse rows
    // 4096 blocks x 512 threads; 16 rows/block; XCD-affine bh mapping
    scores_topk<<<4096, 512, 0, stream>>>(qcat, kcat, svals, sidxp, scntp);

    // K3 x3: polynomial filter (sparse A applications) — overwrites qcat/kcat
    spmm<<<16384, 256, 0, stream>>>(svals, sidxp, scntp, qkvb, nullptr, v1, resb, alphas, 0);
    spmm<<<16384, 256, 0, stream>>>(svals, sidxp, scntp, qkvb, v1, v2, resb, alphas, 1);
    spmm<<<16384, 256, 0, stream>>>(svals, sidxp, scntp, qkvb, v2, nullptr, resb, alphas, 2);

    // K4: out = res @ Wout + bout
    sgemm_bias<<<dim3(512 / 128, 8192 / 128), 256, 0, stream>>>(
        resb, Wout, bout, out, 8192, 512, 512);
}

// Round 16
// 1004.008 us; speedup vs baseline: 1.2043x; 1.2043x over previous
//
#include <hip/hip_runtime.h>
#include <hip/hip_bf16.h>

// Problem constants: B=4, N=2048, DIM=512, H=8, DH=64, ORDER=3, TOPK=64, INNER=512
#define SLOTS 80   // sparse slots per row (64 + tie headroom)

typedef __bf16 bf16x8 __attribute__((ext_vector_type(8)));
typedef float  f32x4  __attribute__((ext_vector_type(4)));

// ---------------------------------------------------------------------------
// K1/K4: fp32 tiled GEMM with bias (unchanged).
// ---------------------------------------------------------------------------
__global__ __launch_bounds__(256)
void sgemm_bias(const float* __restrict__ A, const float* __restrict__ Bm,
                const float* __restrict__ bias, float* __restrict__ C,
                int M, int N, int K)
{
    __shared__ float As[16][132];
    __shared__ float Bs[16][132];

    const int t  = threadIdx.x;
    const int tx = t & 15, ty = t >> 4;
    const int bm = blockIdx.y << 7, bn = blockIdx.x << 7;

    const int arow = t >> 2,  ak4 = (t & 3) << 2;
    const int bkr  = t >> 5,  bc4 = (t & 31) << 2;

    float4 pa[2], pb[2];
#pragma unroll
    for (int s = 0; s < 2; ++s) {
        pa[s] = *(const float4*)&A[(size_t)(bm + arow + (s << 6)) * K + ak4];
        pb[s] = *(const float4*)&Bm[(size_t)(bkr + (s << 3)) * N + bn + bc4];
    }

    float acc[8][8] = {};

    for (int k0 = 0; k0 < K; k0 += 16) {
        __syncthreads();
#pragma unroll
        for (int s = 0; s < 2; ++s) {
            const int ar = arow + (s << 6);
            As[ak4 + 0][ar] = pa[s].x;
            As[ak4 + 1][ar] = pa[s].y;
            As[ak4 + 2][ar] = pa[s].z;
            As[ak4 + 3][ar] = pa[s].w;
            *(float4*)&Bs[bkr + (s << 3)][bc4] = pb[s];
        }
        __syncthreads();
        if (k0 + 16 < K) {
#pragma unroll
            for (int s = 0; s < 2; ++s) {
                pa[s] = *(const float4*)&A[(size_t)(bm + arow + (s << 6)) * K + k0 + 16 + ak4];
                pb[s] = *(const float4*)&Bm[(size_t)(k0 + 16 + bkr + (s << 3)) * N + bn + bc4];
            }
        }
#pragma unroll
        for (int kk = 0; kk < 16; ++kk) {
            float4 a0 = *(const float4*)&As[kk][(ty << 3) + 0];
            float4 a1 = *(const float4*)&As[kk][(ty << 3) + 4];
            float4 b0 = *(const float4*)&Bs[kk][(tx << 2)];
            float4 b1 = *(const float4*)&Bs[kk][64 + (tx << 2)];
            float ar[8] = {a0.x, a0.y, a0.z, a0.w, a1.x, a1.y, a1.z, a1.w};
            float br[8] = {b0.x, b0.y, b0.z, b0.w, b1.x, b1.y, b1.z, b1.w};
#pragma unroll
            for (int i = 0; i < 8; ++i)
#pragma unroll
                for (int j = 0; j < 8; ++j)
                    acc[i][j] = fmaf(ar[i], br[j], acc[i][j]);
        }
    }

    float bb[8];
#pragma unroll
    for (int j = 0; j < 4; ++j) {
        bb[j]     = bias[bn + (tx << 2) + j];
        bb[j + 4] = bias[bn + 64 + (tx << 2) + j];
    }
#pragma unroll
    for (int i = 0; i < 8; ++i) {
        const size_t row = (size_t)(bm + (ty << 3) + i);
        float4 o0 = {acc[i][0] + bb[0], acc[i][1] + bb[1], acc[i][2] + bb[2], acc[i][3] + bb[3]};
        float4 o1 = {acc[i][4] + bb[4], acc[i][5] + bb[5], acc[i][6] + bb[6], acc[i][7] + bb[7]};
        *(float4*)&C[row * N + bn + (tx << 2)]      = o0;
        *(float4*)&C[row * N + bn + 64 + (tx << 2)] = o1;
    }
}

// ---------------------------------------------------------------------------
// K1b v2: exact bf16x3 split of Q,K into FRAGMENT-PACKED layout:
//   frag[bh][tile][f][lane][j], f = plane*2 + ks  (ks = d>>5)
//   lane = (n&15) | (((d&31)>>3)<<4),  j = d&7
// Pure permutation of R15's planes -> MFMA inputs bit-identical; every
// fragment is 1KB contiguous -> K2 loads fully coalesced.
// ---------------------------------------------------------------------------
__global__ __launch_bounds__(256)
void qk_split(const float* __restrict__ qkv, unsigned short* __restrict__ qfrag,
              unsigned short* __restrict__ kfrag)
{
    const int gid = blockIdx.x * 256 + threadIdx.x;   // 0 .. 4194303
    const int d = gid & 63;
    const int h = (gid >> 6) & 7;
    const int n = (gid >> 9) & 2047;
    const int b = gid >> 20;
    const int bh = (b << 3) + h;

    const size_t src = ((size_t)(b * 2048 + n)) * 1536 + (h << 6) + d;

    const int tb = n >> 4;           // rowblk (q) / col-tile (k)
    const int c  = n & 15;
    const int ks = d >> 5;
    const int kk = d & 31;
    const int ln = c | ((kk >> 3) << 4);
    const int j  = kk & 7;
    const size_t base = ((((size_t)bh * 128 + tb) * 6 + ks) * 64 + ln) * 8 + j;

#pragma unroll
    for (int qk = 0; qk < 2; ++qk) {
        const float x = qkv[src + (qk ? 512 : 0)];
        unsigned short* out = qk ? kfrag : qfrag;
        __hip_bfloat16 h0 = __float2bfloat16(x);
        const float f0 = __bfloat162float(h0);
        const float r1 = x - f0;
        __hip_bfloat16 h1 = __float2bfloat16(r1);
        const float f1 = __bfloat162float(h1);
        const float r2 = r1 - f1;
        __hip_bfloat16 h2 = __float2bfloat16(r2);
        out[base]        = *(unsigned short*)&h0;   // f = 0*2+ks (hi)
        out[base + 1024] = *(unsigned short*)&h1;   // f = 1*2+ks (mid)
        out[base + 2048] = *(unsigned short*)&h2;   // f = 2*2+ks (lo)
    }
}

// ---------------------------------------------------------------------------
// K2 v16: MFMA QK^T with COALESCED fragment loads (1KB wave-loads from the
// packed layout) + S stride 2052 (inter-group write distance == 16 mod 32
// -> 2-way, free). MFMA chain order IDENTICAL to R15 -> bit-identical
// scores -> absmax stays exactly 4.119873e-3.
// ---------------------------------------------------------------------------
__global__ __launch_bounds__(512, 2)
void scores_topk(const unsigned short* __restrict__ qfrag,
                 const unsigned short* __restrict__ kfrag,
                 float* __restrict__ svals,
                 unsigned short* __restrict__ sidx, int* __restrict__ scnt)
{
    __shared__ float S[16][2052];   // 131328 B

    const int t    = threadIdx.x;
    const int lane = t & 63;
    const int wid  = t >> 6;                        // 0..7
    const int id   = blockIdx.x;                    // 0..4095
    const int bh   = ((id >> 10) << 3) | (id & 7);  // XCD-affine, bijective
    const int rowblk = (id >> 3) & 127;
    const int r0   = rowblk << 4;                   // block's 16 rows

    // A fragments: one coalesced 16B/lane load per fragment
    const bf16x8* qf = (const bf16x8*)qfrag
                     + (((size_t)bh * 128 + rowblk) * 6) * 64 + lane;
    bf16x8 afr[6];
#pragma unroll
    for (int f = 0; f < 6; ++f) afr[f] = qf[f * 64];

    const bf16x8* kf = (const bf16x8*)kfrag + ((size_t)bh * 128 * 6) * 64 + lane;

#pragma unroll 1
    for (int i = 0; i < 16; ++i) {
        const int ct = (i << 3) + wid;              // wave's col-tile
        const bf16x8* kb = kf + (size_t)ct * 384;   // 6 fragments x 64 groups
        bf16x8 b0 = kb[0];
        bf16x8 b1 = kb[64];
        bf16x8 b2 = kb[128];
        bf16x8 b3 = kb[192];
        bf16x8 b4 = kb[256];
        bf16x8 b5 = kb[320];

        f32x4 acc = {0.f, 0.f, 0.f, 0.f};
        acc = __builtin_amdgcn_mfma_f32_16x16x32_bf16(afr[0], b0, acc, 0, 0, 0); // hi.hi
        acc = __builtin_amdgcn_mfma_f32_16x16x32_bf16(afr[1], b1, acc, 0, 0, 0);
        acc = __builtin_amdgcn_mfma_f32_16x16x32_bf16(afr[0], b2, acc, 0, 0, 0); // hi.mid
        acc = __builtin_amdgcn_mfma_f32_16x16x32_bf16(afr[1], b3, acc, 0, 0, 0);
        acc = __builtin_amdgcn_mfma_f32_16x16x32_bf16(afr[2], b0, acc, 0, 0, 0); // mid.hi
        acc = __builtin_amdgcn_mfma_f32_16x16x32_bf16(afr[3], b1, acc, 0, 0, 0);
        acc = __builtin_amdgcn_mfma_f32_16x16x32_bf16(afr[2], b2, acc, 0, 0, 0); // mid.mid
        acc = __builtin_amdgcn_mfma_f32_16x16x32_bf16(afr[3], b3, acc, 0, 0, 0);
        acc = __builtin_amdgcn_mfma_f32_16x16x32_bf16(afr[0], b4, acc, 0, 0, 0); // hi.lo
        acc = __builtin_amdgcn_mfma_f32_16x16x32_bf16(afr[1], b5, acc, 0, 0, 0);
        acc = __builtin_amdgcn_mfma_f32_16x16x32_bf16(afr[4], b0, acc, 0, 0, 0); // lo.hi
        acc = __builtin_amdgcn_mfma_f32_16x16x32_bf16(afr[5], b1, acc, 0, 0, 0);

        const int col   = (ct << 4) + (lane & 15);
        const int rbase = (lane >> 4) << 2;
#pragma unroll
        for (int reg = 0; reg < 4; ++reg)
            S[rbase + reg][col] = acc[reg] * 0.125f;
    }
    __syncthreads();

    // phase B: 2 rows/wave; exact 64th-largest via early-exit bisection
    const unsigned long long pre64 = (1ull << lane) - 1ull;

#define PHASEB(RQ)                                                             \
    {                                                                          \
        const int rr = (wid << 1) + (RQ);                                      \
        float    fv[32];                                                       \
        unsigned uv[32];                                                       \
        _Pragma("unroll")                                                      \
        for (int m = 0; m < 32; ++m) {                                         \
            const float x = S[rr][lane + (m << 6)];                            \
            fv[m] = x;                                                         \
            const unsigned bx = __float_as_uint(x);                            \
            uv[m] = bx ^ (unsigned)(((int)bx >> 31) | 0x80000000);             \
        }                                                                      \
        unsigned lo = 0;                                                       \
        _Pragma("unroll 1")                                                    \
        for (int bit = 31; bit >= 0; --bit) {                                  \
            const unsigned mid = lo | (1u << bit);                             \
            int c = 0;                                                         \
            _Pragma("unroll")                                                  \
            for (int m = 0; m < 32; ++m)                                       \
                c += __popcll(__ballot(uv[m] >= mid));                         \
            if (c >= 64) {                                                     \
                lo = mid;                                                      \
                if (c == 64) break;                                            \
            }                                                                  \
        }                                                                      \
        unsigned um = 0;                                                       \
        _Pragma("unroll")                                                      \
        for (int m = 0; m < 32; ++m) um = uv[m] > um ? uv[m] : um;             \
        _Pragma("unroll")                                                      \
        for (int off = 1; off < 64; off <<= 1) {                               \
            const unsigned o = (unsigned)__shfl_xor((int)um, off, 64);         \
            um = o > um ? o : um;                                              \
        }                                                                      \
        const unsigned mbm = (um & 0x80000000u) ? (um ^ 0x80000000u) : ~um;    \
        const float Mx = __uint_as_float(mbm);                                 \
        float zs = 0.f;                                                        \
        _Pragma("unroll")                                                      \
        for (int m = 0; m < 32; ++m) {                                         \
            const bool keep = uv[m] >= lo;                                     \
            const float ex = keep ? __expf(fv[m] - Mx) : 0.f;                  \
            fv[m] = ex;                                                        \
            zs += ex;                                                          \
        }                                                                      \
        _Pragma("unroll")                                                      \
        for (int off = 1; off < 64; off <<= 1) zs += __shfl_xor(zs, off, 64);  \
        const float zinv = 1.0f / zs;                                          \
        const size_t grow = (size_t)bh * 2048 + r0 + rr;                       \
        float* vd           = svals + grow * SLOTS;                            \
        unsigned short* idp = sidx  + grow * SLOTS;                            \
        int base = 0;                                                          \
        _Pragma("unroll")                                                      \
        for (int m = 0; m < 32; ++m) {                                         \
            const bool keep = uv[m] >= lo;                                     \
            unsigned long long ball = __ballot(keep);                          \
            if (keep) {                                                        \
                const int my = base + __popcll(ball & pre64);                  \
                if (my < SLOTS) {                                              \
                    vd[my]  = fv[m] * zinv;                                    \
                    idp[my] = (unsigned short)(lane + (m << 6));               \
                }                                                              \
            }                                                                  \
            base += __popcll(ball);                                            \
        }                                                                      \
        if (lane == 0) scnt[grow] = base < SLOTS ? base : SLOTS;               \
    }

    PHASEB(0)
    PHASEB(1)
#undef PHASEB
}

// ---------------------------------------------------------------------------
// K3: sparse attn application (unchanged: x8 unroll + XCD-affine).
// ---------------------------------------------------------------------------
__global__ __launch_bounds__(256)
void spmm(const float* __restrict__ svals, const unsigned short* __restrict__ sidx,
          const int* __restrict__ scnt, const float* __restrict__ qkv,
          const float* __restrict__ vin, float* __restrict__ vout,
          float* __restrict__ res, const float* __restrict__ alphas_raw, int order)
{
    const int lane = threadIdx.x & 63;
    const int id   = blockIdx.x;                      // 0..16383
    const int bh   = ((id & 7) << 2) | (id >> 12);    // XCD-affine, bijective
    const int nblk = (id >> 3) & 511;
    const int n    = (nblk << 2) + (threadIdx.x >> 6);
    const int gr   = (bh << 11) + n;
    const int b    = bh >> 3,  h = bh & 7;

    const float* vb;
    int stride;
    if (order == 0) { vb = qkv + (size_t)b * 2048 * 1536 + 1024 + (h << 6); stride = 1536; }
    else            { vb = vin + ((size_t)bh << 17);                        stride = 64;   }

    const int cnt = scnt[gr];
    const float* va          = svals + (size_t)gr * SLOTS;
    const unsigned short* ia = sidx  + (size_t)gr * SLOTS;

    float acc = 0.f;
    int j = 0;
    for (; j + 8 <= cnt; j += 8) {
        float a0 = va[j],     a1 = va[j + 1], a2 = va[j + 2], a3 = va[j + 3];
        float a4 = va[j + 4], a5 = va[j + 5], a6 = va[j + 6], a7 = va[j + 7];
        int   i0 = ia[j],     i1 = ia[j + 1], i2 = ia[j + 2], i3 = ia[j + 3];
        int   i4 = ia[j + 4], i5 = ia[j + 5], i6 = ia[j + 6], i7 = ia[j + 7];
        acc += a0 * vb[(size_t)i0 * stride + lane];
        acc += a1 * vb[(size_t)i1 * stride + lane];
        acc += a2 * vb[(size_t)i2 * stride + lane];
        acc += a3 * vb[(size_t)i3 * stride + lane];
        acc += a4 * vb[(size_t)i4 * stride + lane];
        acc += a5 * vb[(size_t)i5 * stride + lane];
        acc += a6 * vb[(size_t)i6 * stride + lane];
        acc += a7 * vb[(size_t)i7 * stride + lane];
    }
    for (; j < cnt; ++j) acc += va[j] * vb[(size_t)ia[j] * stride + lane];

    if (order < 2) vout[((size_t)gr << 6) + lane] = acc;

    float ar    = alphas_raw[(order << 3) + h];
    float alpha = ar * 0.5f * (1.0f + erff(ar * 0.70710678f));  // exact gelu
    size_t ro = ((size_t)b * 2048 + n) * 512 + (h << 6) + lane;
    float av  = alpha * acc;
    if (order == 0) res[ro] = av;
    else            res[ro] += av;
}

// ---------------------------------------------------------------------------
extern "C" void kernel_launch(void* const* d_in, const int* in_sizes, int n_in,
                              void* d_out, int out_size, void* d_ws, size_t ws_size,
                              hipStream_t stream)
{
    const float* x      = (const float*)d_in[0];
    const float* Wqkv   = (const float*)d_in[1];
    const float* bqkv   = (const float*)d_in[2];
    const float* Wout   = (const float*)d_in[3];
    const float* bout   = (const float*)d_in[4];
    const float* alphas = (const float*)d_in[5];
    float* out = (float*)d_out;

    // workspace layout (bytes)
    char* ws = (char*)d_ws;
    float*          qkvb  = (float*)ws;                       // 50331648
    float*          svals = (float*)(ws + 50331648);          // 20971520
    unsigned short* sidxp = (unsigned short*)(ws + 71303168); // 10485760
    int*            scntp = (int*)(ws + 81788928);            // 262144
    // v1/v2/resb region (50331648 B at +82051072) is time-shared:
    //  - during K1b/K2: qfrag (25165824) + kfrag (25165824)
    //  - during spmm/K4: v1, v2, resb (3 x 16777216)
    unsigned short* qfrag = (unsigned short*)(ws + 82051072);
    unsigned short* kfrag = (unsigned short*)(ws + 107216896);
    float*          v1    = (float*)(ws + 82051072);
    float*          v2    = (float*)(ws + 98828288);
    float*          resb  = (float*)(ws + 115605504);
    if (ws_size < 132382720) return;                          // need ~126 MB

    // K1: qkv = x @ Wqkv + bqkv
    sgemm_bias<<<dim3(1536 / 128, 8192 / 128), 256, 0, stream>>>(
        x, Wqkv, bqkv, qkvb, 8192, 1536, 512);

    // K1b: exact bf16x3 split of Q,K into fragment-packed layout
    qk_split<<<16384, 256, 0, stream>>>(qkvb, qfrag, kfrag);

    // K2: MFMA scores -> exact top-64(+ties) -> softmax -> sparse rows
    scores_topk<<<4096, 512, 0, stream>>>(qfrag, kfrag, svals, sidxp, scntp);

    // K3 x3: polynomial filter (sparse A applications) — overwrites q/kfrag
    spmm<<<16384, 256, 0, stream>>>(svals, sidxp, scntp, qkvb, nullptr, v1, resb, alphas, 0);
    spmm<<<16384, 256, 0, stream>>>(svals, sidxp, scntp, qkvb, v1, v2, resb, alphas, 1);
    spmm<<<16384, 256, 0, stream>>>(svals, sidxp, scntp, qkvb, v2, nullptr, resb, alphas, 2);

    // K4: out = res @ Wout + bout
    sgemm_bias<<<dim3(512 / 128, 8192 / 128), 256, 0, stream>>>(
        resb, Wout, bout, out, 8192, 512, 512);
}

// Round 17
// 996.672 us; speedup vs baseline: 1.2132x; 1.0074x over previous
//
#include <hip/hip_runtime.h>
#include <hip/hip_bf16.h>

// Problem constants: B=4, N=2048, DIM=512, H=8, DH=64, ORDER=3, TOPK=64, INNER=512
#define SLOTS 80   // sparse slots per row (64 + tie headroom)

typedef __bf16 bf16x8 __attribute__((ext_vector_type(8)));
typedef float  f32x4  __attribute__((ext_vector_type(4)));

// ---------------------------------------------------------------------------
// K1/K4: fp32 tiled GEMM with bias (unchanged).
// ---------------------------------------------------------------------------
__global__ __launch_bounds__(256)
void sgemm_bias(const float* __restrict__ A, const float* __restrict__ Bm,
                const float* __restrict__ bias, float* __restrict__ C,
                int M, int N, int K)
{
    __shared__ float As[16][132];
    __shared__ float Bs[16][132];

    const int t  = threadIdx.x;
    const int tx = t & 15, ty = t >> 4;
    const int bm = blockIdx.y << 7, bn = blockIdx.x << 7;

    const int arow = t >> 2,  ak4 = (t & 3) << 2;
    const int bkr  = t >> 5,  bc4 = (t & 31) << 2;

    float4 pa[2], pb[2];
#pragma unroll
    for (int s = 0; s < 2; ++s) {
        pa[s] = *(const float4*)&A[(size_t)(bm + arow + (s << 6)) * K + ak4];
        pb[s] = *(const float4*)&Bm[(size_t)(bkr + (s << 3)) * N + bn + bc4];
    }

    float acc[8][8] = {};

    for (int k0 = 0; k0 < K; k0 += 16) {
        __syncthreads();
#pragma unroll
        for (int s = 0; s < 2; ++s) {
            const int ar = arow + (s << 6);
            As[ak4 + 0][ar] = pa[s].x;
            As[ak4 + 1][ar] = pa[s].y;
            As[ak4 + 2][ar] = pa[s].z;
            As[ak4 + 3][ar] = pa[s].w;
            *(float4*)&Bs[bkr + (s << 3)][bc4] = pb[s];
        }
        __syncthreads();
        if (k0 + 16 < K) {
#pragma unroll
            for (int s = 0; s < 2; ++s) {
                pa[s] = *(const float4*)&A[(size_t)(bm + arow + (s << 6)) * K + k0 + 16 + ak4];
                pb[s] = *(const float4*)&Bm[(size_t)(k0 + 16 + bkr + (s << 3)) * N + bn + bc4];
            }
        }
#pragma unroll
        for (int kk = 0; kk < 16; ++kk) {
            float4 a0 = *(const float4*)&As[kk][(ty << 3) + 0];
            float4 a1 = *(const float4*)&As[kk][(ty << 3) + 4];
            float4 b0 = *(const float4*)&Bs[kk][(tx << 2)];
            float4 b1 = *(const float4*)&Bs[kk][64 + (tx << 2)];
            float ar[8] = {a0.x, a0.y, a0.z, a0.w, a1.x, a1.y, a1.z, a1.w};
            float br[8] = {b0.x, b0.y, b0.z, b0.w, b1.x, b1.y, b1.z, b1.w};
#pragma unroll
            for (int i = 0; i < 8; ++i)
#pragma unroll
                for (int j = 0; j < 8; ++j)
                    acc[i][j] = fmaf(ar[i], br[j], acc[i][j]);
        }
    }

    float bb[8];
#pragma unroll
    for (int j = 0; j < 4; ++j) {
        bb[j]     = bias[bn + (tx << 2) + j];
        bb[j + 4] = bias[bn + 64 + (tx << 2) + j];
    }
#pragma unroll
    for (int i = 0; i < 8; ++i) {
        const size_t row = (size_t)(bm + (ty << 3) + i);
        float4 o0 = {acc[i][0] + bb[0], acc[i][1] + bb[1], acc[i][2] + bb[2], acc[i][3] + bb[3]};
        float4 o1 = {acc[i][4] + bb[4], acc[i][5] + bb[5], acc[i][6] + bb[6], acc[i][7] + bb[7]};
        *(float4*)&C[row * N + bn + (tx << 2)]      = o0;
        *(float4*)&C[row * N + bn + 64 + (tx << 2)] = o1;
    }
}

// ---------------------------------------------------------------------------
// K1b: exact bf16x3 split of Q,K into fragment-packed layout (unchanged).
// ---------------------------------------------------------------------------
__global__ __launch_bounds__(256)
void qk_split(const float* __restrict__ qkv, unsigned short* __restrict__ qfrag,
              unsigned short* __restrict__ kfrag)
{
    const int gid = blockIdx.x * 256 + threadIdx.x;   // 0 .. 4194303
    const int d = gid & 63;
    const int h = (gid >> 6) & 7;
    const int n = (gid >> 9) & 2047;
    const int b = gid >> 20;
    const int bh = (b << 3) + h;

    const size_t src = ((size_t)(b * 2048 + n)) * 1536 + (h << 6) + d;

    const int tb = n >> 4;           // rowblk (q) / col-tile (k)
    const int c  = n & 15;
    const int ks = d >> 5;
    const int kk = d & 31;
    const int ln = c | ((kk >> 3) << 4);
    const int j  = kk & 7;
    const size_t base = ((((size_t)bh * 128 + tb) * 6 + ks) * 64 + ln) * 8 + j;

#pragma unroll
    for (int qk = 0; qk < 2; ++qk) {
        const float x = qkv[src + (qk ? 512 : 0)];
        unsigned short* out = qk ? kfrag : qfrag;
        __hip_bfloat16 h0 = __float2bfloat16(x);
        const float f0 = __bfloat162float(h0);
        const float r1 = x - f0;
        __hip_bfloat16 h1 = __float2bfloat16(r1);
        const float f1 = __bfloat162float(h1);
        const float r2 = r1 - f1;
        __hip_bfloat16 h2 = __float2bfloat16(r2);
        out[base]        = *(unsigned short*)&h0;   // hi
        out[base + 1024] = *(unsigned short*)&h1;   // mid
        out[base + 2048] = *(unsigned short*)&h2;   // lo
    }
}

// ---------------------------------------------------------------------------
// K2 v17 = R16 + DEPTH-2 REGISTER PIPELINE on B fragments: STEP(I) issues
// iter I+1's 6 coalesced loads into the idle named buffer (A/B alternating,
// all indices literal) before iter I's 12-MFMA chain, giving each load a
// full iteration (x 2 waves/SIMD interleave) to complete. No fences.
// Load values and MFMA chain order identical to R16 -> bit-identical scores
// (absmax stays exactly 4.119873e-3).
// ---------------------------------------------------------------------------
__global__ __launch_bounds__(512, 2)
void scores_topk(const unsigned short* __restrict__ qfrag,
                 const unsigned short* __restrict__ kfrag,
                 float* __restrict__ svals,
                 unsigned short* __restrict__ sidx, int* __restrict__ scnt)
{
    __shared__ float S[16][2052];   // 131328 B

    const int t    = threadIdx.x;
    const int lane = t & 63;
    const int wid  = t >> 6;                        // 0..7
    const int id   = blockIdx.x;                    // 0..4095
    const int bh   = ((id >> 10) << 3) | (id & 7);  // XCD-affine, bijective
    const int rowblk = (id >> 3) & 127;
    const int r0   = rowblk << 4;                   // block's 16 rows

    // A fragments: one coalesced 16B/lane load per fragment
    const bf16x8* qf = (const bf16x8*)qfrag
                     + (((size_t)bh * 128 + rowblk) * 6) * 64 + lane;
    bf16x8 afr[6];
#pragma unroll
    for (int f = 0; f < 6; ++f) afr[f] = qf[f * 64];

    const bf16x8* kf = (const bf16x8*)kfrag + ((size_t)bh * 128 * 6) * 64 + lane;

    bf16x8 A0, A1, A2, A3, A4, A5;   // pipeline buffer A
    bf16x8 B0, B1, B2, B3, B4, B5;   // pipeline buffer B

#define LOADB(I, P)                                                            \
    {                                                                          \
        const bf16x8* kb = kf + (size_t)(((I) << 3) + wid) * 384;              \
        P##0 = kb[0];   P##1 = kb[64];  P##2 = kb[128];                        \
        P##3 = kb[192]; P##4 = kb[256]; P##5 = kb[320];                        \
    }

#define STEP(I, C, N)                                                          \
    {                                                                          \
        if ((I) < 15) LOADB((I) + 1, N)                                        \
        f32x4 acc = {0.f, 0.f, 0.f, 0.f};                                      \
        acc = __builtin_amdgcn_mfma_f32_16x16x32_bf16(afr[0], C##0, acc, 0, 0, 0); \
        acc = __builtin_amdgcn_mfma_f32_16x16x32_bf16(afr[1], C##1, acc, 0, 0, 0); \
        acc = __builtin_amdgcn_mfma_f32_16x16x32_bf16(afr[0], C##2, acc, 0, 0, 0); \
        acc = __builtin_amdgcn_mfma_f32_16x16x32_bf16(afr[1], C##3, acc, 0, 0, 0); \
        acc = __builtin_amdgcn_mfma_f32_16x16x32_bf16(afr[2], C##0, acc, 0, 0, 0); \
        acc = __builtin_amdgcn_mfma_f32_16x16x32_bf16(afr[3], C##1, acc, 0, 0, 0); \
        acc = __builtin_amdgcn_mfma_f32_16x16x32_bf16(afr[2], C##2, acc, 0, 0, 0); \
        acc = __builtin_amdgcn_mfma_f32_16x16x32_bf16(afr[3], C##3, acc, 0, 0, 0); \
        acc = __builtin_amdgcn_mfma_f32_16x16x32_bf16(afr[0], C##4, acc, 0, 0, 0); \
        acc = __builtin_amdgcn_mfma_f32_16x16x32_bf16(afr[1], C##5, acc, 0, 0, 0); \
        acc = __builtin_amdgcn_mfma_f32_16x16x32_bf16(afr[4], C##0, acc, 0, 0, 0); \
        acc = __builtin_amdgcn_mfma_f32_16x16x32_bf16(afr[5], C##1, acc, 0, 0, 0); \
        const int col   = ((((I) << 3) + wid) << 4) + (lane & 15);             \
        const int rbase = (lane >> 4) << 2;                                    \
        S[rbase + 0][col] = acc[0] * 0.125f;                                   \
        S[rbase + 1][col] = acc[1] * 0.125f;                                   \
        S[rbase + 2][col] = acc[2] * 0.125f;                                   \
        S[rbase + 3][col] = acc[3] * 0.125f;                                   \
    }

    LOADB(0, A)
    STEP(0,  A, B) STEP(1,  B, A) STEP(2,  A, B) STEP(3,  B, A)
    STEP(4,  A, B) STEP(5,  B, A) STEP(6,  A, B) STEP(7,  B, A)
    STEP(8,  A, B) STEP(9,  B, A) STEP(10, A, B) STEP(11, B, A)
    STEP(12, A, B) STEP(13, B, A) STEP(14, A, B) STEP(15, B, A)
#undef STEP
#undef LOADB

    __syncthreads();

    // phase B: 2 rows/wave; exact 64th-largest via early-exit bisection
    const unsigned long long pre64 = (1ull << lane) - 1ull;

#define PHASEB(RQ)                                                             \
    {                                                                          \
        const int rr = (wid << 1) + (RQ);                                      \
        float    fv[32];                                                       \
        unsigned uv[32];                                                       \
        _Pragma("unroll")                                                      \
        for (int m = 0; m < 32; ++m) {                                         \
            const float x = S[rr][lane + (m << 6)];                            \
            fv[m] = x;                                                         \
            const unsigned bx = __float_as_uint(x);                            \
            uv[m] = bx ^ (unsigned)(((int)bx >> 31) | 0x80000000);             \
        }                                                                      \
        unsigned lo = 0;                                                       \
        _Pragma("unroll 1")                                                    \
        for (int bit = 31; bit >= 0; --bit) {                                  \
            const unsigned mid = lo | (1u << bit);                             \
            int c = 0;                                                         \
            _Pragma("unroll")                                                  \
            for (int m = 0; m < 32; ++m)                                       \
                c += __popcll(__ballot(uv[m] >= mid));                         \
            if (c >= 64) {                                                     \
                lo = mid;                                                      \
                if (c == 64) break;                                            \
            }                                                                  \
        }                                                                      \
        unsigned um = 0;                                                       \
        _Pragma("unroll")                                                      \
        for (int m = 0; m < 32; ++m) um = uv[m] > um ? uv[m] : um;             \
        _Pragma("unroll")                                                      \
        for (int off = 1; off < 64; off <<= 1) {                               \
            const unsigned o = (unsigned)__shfl_xor((int)um, off, 64);         \
            um = o > um ? o : um;                                              \
        }                                                                      \
        const unsigned mbm = (um & 0x80000000u) ? (um ^ 0x80000000u) : ~um;    \
        const float Mx = __uint_as_float(mbm);                                 \
        float zs = 0.f;                                                        \
        _Pragma("unroll")                                                      \
        for (int m = 0; m < 32; ++m) {                                         \
            const bool keep = uv[m] >= lo;                                     \
            const float ex = keep ? __expf(fv[m] - Mx) : 0.f;                  \
            fv[m] = ex;                                                        \
            zs += ex;                                                          \
        }                                                                      \
        _Pragma("unroll")                                                      \
        for (int off = 1; off < 64; off <<= 1) zs += __shfl_xor(zs, off, 64);  \
        const float zinv = 1.0f / zs;                                          \
        const size_t grow = (size_t)bh * 2048 + r0 + rr;                       \
        float* vd           = svals + grow * SLOTS;                            \
        unsigned short* idp = sidx  + grow * SLOTS;                            \
        int base = 0;                                                          \
        _Pragma("unroll")                                                      \
        for (int m = 0; m < 32; ++m) {                                         \
            const bool keep = uv[m] >= lo;                                     \
            unsigned long long ball = __ballot(keep);                          \
            if (keep) {                                                        \
                const int my = base + __popcll(ball & pre64);                  \
                if (my < SLOTS) {                                              \
                    vd[my]  = fv[m] * zinv;                                    \
                    idp[my] = (unsigned short)(lane + (m << 6));               \
                }                                                              \
            }                                                                  \
            base += __popcll(ball);                                            \
        }                                                                      \
        if (lane == 0) scnt[grow] = base < SLOTS ? base : SLOTS;               \
    }

    PHASEB(0)
    PHASEB(1)
#undef PHASEB
}

// ---------------------------------------------------------------------------
// K3: sparse attn application (unchanged: x8 unroll + XCD-affine).
// ---------------------------------------------------------------------------
__global__ __launch_bounds__(256)
void spmm(const float* __restrict__ svals, const unsigned short* __restrict__ sidx,
          const int* __restrict__ scnt, const float* __restrict__ qkv,
          const float* __restrict__ vin, float* __restrict__ vout,
          float* __restrict__ res, const float* __restrict__ alphas_raw, int order)
{
    const int lane = threadIdx.x & 63;
    const int id   = blockIdx.x;                      // 0..16383
    const int bh   = ((id & 7) << 2) | (id >> 12);    // XCD-affine, bijective
    const int nblk = (id >> 3) & 511;
    const int n    = (nblk << 2) + (threadIdx.x >> 6);
    const int gr   = (bh << 11) + n;
    const int b    = bh >> 3,  h = bh & 7;

    const float* vb;
    int stride;
    if (order == 0) { vb = qkv + (size_t)b * 2048 * 1536 + 1024 + (h << 6); stride = 1536; }
    else            { vb = vin + ((size_t)bh << 17);                        stride = 64;   }

    const int cnt = scnt[gr];
    const float* va          = svals + (size_t)gr * SLOTS;
    const unsigned short* ia = sidx  + (size_t)gr * SLOTS;

    float acc = 0.f;
    int j = 0;
    for (; j + 8 <= cnt; j += 8) {
        float a0 = va[j],     a1 = va[j + 1], a2 = va[j + 2], a3 = va[j + 3];
        float a4 = va[j + 4], a5 = va[j + 5], a6 = va[j + 6], a7 = va[j + 7];
        int   i0 = ia[j],     i1 = ia[j + 1], i2 = ia[j + 2], i3 = ia[j + 3];
        int   i4 = ia[j + 4], i5 = ia[j + 5], i6 = ia[j + 6], i7 = ia[j + 7];
        acc += a0 * vb[(size_t)i0 * stride + lane];
        acc += a1 * vb[(size_t)i1 * stride + lane];
        acc += a2 * vb[(size_t)i2 * stride + lane];
        acc += a3 * vb[(size_t)i3 * stride + lane];
        acc += a4 * vb[(size_t)i4 * stride + lane];
        acc += a5 * vb[(size_t)i5 * stride + lane];
        acc += a6 * vb[(size_t)i6 * stride + lane];
        acc += a7 * vb[(size_t)i7 * stride + lane];
    }
    for (; j < cnt; ++j) acc += va[j] * vb[(size_t)ia[j] * stride + lane];

    if (order < 2) vout[((size_t)gr << 6) + lane] = acc;

    float ar    = alphas_raw[(order << 3) + h];
    float alpha = ar * 0.5f * (1.0f + erff(ar * 0.70710678f));  // exact gelu
    size_t ro = ((size_t)b * 2048 + n) * 512 + (h << 6) + lane;
    float av  = alpha * acc;
    if (order == 0) res[ro] = av;
    else            res[ro] += av;
}

// ---------------------------------------------------------------------------
extern "C" void kernel_launch(void* const* d_in, const int* in_sizes, int n_in,
                              void* d_out, int out_size, void* d_ws, size_t ws_size,
                              hipStream_t stream)
{
    const float* x      = (const float*)d_in[0];
    const float* Wqkv   = (const float*)d_in[1];
    const float* bqkv   = (const float*)d_in[2];
    const float* Wout   = (const float*)d_in[3];
    const float* bout   = (const float*)d_in[4];
    const float* alphas = (const float*)d_in[5];
    float* out = (float*)d_out;

    // workspace layout (bytes)
    char* ws = (char*)d_ws;
    float*          qkvb  = (float*)ws;                       // 50331648
    float*          svals = (float*)(ws + 50331648);          // 20971520
    unsigned short* sidxp = (unsigned short*)(ws + 71303168); // 10485760
    int*            scntp = (int*)(ws + 81788928);            // 262144
    // v1/v2/resb region (50331648 B at +82051072) is time-shared:
    //  - during K1b/K2: qfrag (25165824) + kfrag (25165824)
    //  - during spmm/K4: v1, v2, resb (3 x 16777216)
    unsigned short* qfrag = (unsigned short*)(ws + 82051072);
    unsigned short* kfrag = (unsigned short*)(ws + 107216896);
    float*          v1    = (float*)(ws + 82051072);
    float*          v2    = (float*)(ws + 98828288);
    float*          resb  = (float*)(ws + 115605504);
    if (ws_size < 132382720) return;                          // need ~126 MB

    // K1: qkv = x @ Wqkv + bqkv
    sgemm_bias<<<dim3(1536 / 128, 8192 / 128), 256, 0, stream>>>(
        x, Wqkv, bqkv, qkvb, 8192, 1536, 512);

    // K1b: exact bf16x3 split of Q,K into fragment-packed layout
    qk_split<<<16384, 256, 0, stream>>>(qkvb, qfrag, kfrag);

    // K2: MFMA scores -> exact top-64(+ties) -> softmax -> sparse rows
    scores_topk<<<4096, 512, 0, stream>>>(qfrag, kfrag, svals, sidxp, scntp);

    // K3 x3: polynomial filter (sparse A applications) — overwrites q/kfrag
    spmm<<<16384, 256, 0, stream>>>(svals, sidxp, scntp, qkvb, nullptr, v1, resb, alphas, 0);
    spmm<<<16384, 256, 0, stream>>>(svals, sidxp, scntp, qkvb, v1, v2, resb, alphas, 1);
    spmm<<<16384, 256, 0, stream>>>(svals, sidxp, scntp, qkvb, v2, nullptr, resb, alphas, 2);

    // K4: out = res @ Wout + bout
    sgemm_bias<<<dim3(512 / 128, 8192 / 128), 256, 0, stream>>>(
        resb, Wout, bout, out, 8192, 512, 512);
}

// Round 18
// 974.254 us; speedup vs baseline: 1.2411x; 1.0230x over previous
//
#include <hip/hip_runtime.h>
#include <hip/hip_bf16.h>

// Problem constants: B=4, N=2048, DIM=512, H=8, DH=64, ORDER=3, TOPK=64, INNER=512
#define SLOTS 80   // sparse slots per row (64 + tie headroom)

typedef __bf16 bf16x8 __attribute__((ext_vector_type(8)));
typedef float  f32x4  __attribute__((ext_vector_type(4)));
typedef unsigned short u16x8 __attribute__((ext_vector_type(8)));

// ---------------------------------------------------------------------------
// K1/K4: fp32 tiled GEMM with bias (unchanged).
// ---------------------------------------------------------------------------
__global__ __launch_bounds__(256)
void sgemm_bias(const float* __restrict__ A, const float* __restrict__ Bm,
                const float* __restrict__ bias, float* __restrict__ C,
                int M, int N, int K)
{
    __shared__ float As[16][132];
    __shared__ float Bs[16][132];

    const int t  = threadIdx.x;
    const int tx = t & 15, ty = t >> 4;
    const int bm = blockIdx.y << 7, bn = blockIdx.x << 7;

    const int arow = t >> 2,  ak4 = (t & 3) << 2;
    const int bkr  = t >> 5,  bc4 = (t & 31) << 2;

    float4 pa[2], pb[2];
#pragma unroll
    for (int s = 0; s < 2; ++s) {
        pa[s] = *(const float4*)&A[(size_t)(bm + arow + (s << 6)) * K + ak4];
        pb[s] = *(const float4*)&Bm[(size_t)(bkr + (s << 3)) * N + bn + bc4];
    }

    float acc[8][8] = {};

    for (int k0 = 0; k0 < K; k0 += 16) {
        __syncthreads();
#pragma unroll
        for (int s = 0; s < 2; ++s) {
            const int ar = arow + (s << 6);
            As[ak4 + 0][ar] = pa[s].x;
            As[ak4 + 1][ar] = pa[s].y;
            As[ak4 + 2][ar] = pa[s].z;
            As[ak4 + 3][ar] = pa[s].w;
            *(float4*)&Bs[bkr + (s << 3)][bc4] = pb[s];
        }
        __syncthreads();
        if (k0 + 16 < K) {
#pragma unroll
            for (int s = 0; s < 2; ++s) {
                pa[s] = *(const float4*)&A[(size_t)(bm + arow + (s << 6)) * K + k0 + 16 + ak4];
                pb[s] = *(const float4*)&Bm[(size_t)(k0 + 16 + bkr + (s << 3)) * N + bn + bc4];
            }
        }
#pragma unroll
        for (int kk = 0; kk < 16; ++kk) {
            float4 a0 = *(const float4*)&As[kk][(ty << 3) + 0];
            float4 a1 = *(const float4*)&As[kk][(ty << 3) + 4];
            float4 b0 = *(const float4*)&Bs[kk][(tx << 2)];
            float4 b1 = *(const float4*)&Bs[kk][64 + (tx << 2)];
            float ar[8] = {a0.x, a0.y, a0.z, a0.w, a1.x, a1.y, a1.z, a1.w};
            float br[8] = {b0.x, b0.y, b0.z, b0.w, b1.x, b1.y, b1.z, b1.w};
#pragma unroll
            for (int i = 0; i < 8; ++i)
#pragma unroll
                for (int j = 0; j < 8; ++j)
                    acc[i][j] = fmaf(ar[i], br[j], acc[i][j]);
        }
    }

    float bb[8];
#pragma unroll
    for (int j = 0; j < 4; ++j) {
        bb[j]     = bias[bn + (tx << 2) + j];
        bb[j + 4] = bias[bn + 64 + (tx << 2) + j];
    }
#pragma unroll
    for (int i = 0; i < 8; ++i) {
        const size_t row = (size_t)(bm + (ty << 3) + i);
        float4 o0 = {acc[i][0] + bb[0], acc[i][1] + bb[1], acc[i][2] + bb[2], acc[i][3] + bb[3]};
        float4 o1 = {acc[i][4] + bb[4], acc[i][5] + bb[5], acc[i][6] + bb[6], acc[i][7] + bb[7]};
        *(float4*)&C[row * N + bn + (tx << 2)]      = o0;
        *(float4*)&C[row * N + bn + 64 + (tx << 2)] = o1;
    }
}

// ---------------------------------------------------------------------------
// K1b v3: exact bf16x3 split, VECTORIZED: thread owns 8 consecutive d (one
// j-group) -> per plane the 8 ushorts are one contiguous 16B store; reads
// are 32B/thread. Same per-element split math -> bit-identical fragments.
// ---------------------------------------------------------------------------
__global__ __launch_bounds__(256)
void qk_split(const float* __restrict__ qkv, unsigned short* __restrict__ qfrag,
              unsigned short* __restrict__ kfrag)
{
    const int gid = blockIdx.x * 256 + threadIdx.x;   // 0 .. 524287
    const int dg = gid & 7;                            // d-group: d = dg*8+j
    const int h  = (gid >> 3) & 7;
    const int n  = (gid >> 6) & 2047;
    const int b  = gid >> 17;
    const int bh = (b << 3) + h;

    const size_t src = ((size_t)(b * 2048 + n)) * 1536 + (h << 6) + (dg << 3);

    const int tb = n >> 4;
    const int c  = n & 15;
    const int ks = dg >> 2;                 // d>>5
    const int ln = c | ((dg & 3) << 4);     // c | ((kk>>3)<<4)
    const size_t base0 = ((((size_t)bh * 128 + tb) * 6 + ks) * 64 + ln) * 8;

#pragma unroll
    for (int qk = 0; qk < 2; ++qk) {
        const float4 x0 = *(const float4*)&qkv[src + (qk ? 512 : 0)];
        const float4 x1 = *(const float4*)&qkv[src + (qk ? 512 : 0) + 4];
        unsigned short* outp = qk ? kfrag : qfrag;
        const float xs[8] = {x0.x, x0.y, x0.z, x0.w, x1.x, x1.y, x1.z, x1.w};
        u16x8 vh, vm, vl;
#pragma unroll
        for (int j = 0; j < 8; ++j) {
            const float x = xs[j];
            __hip_bfloat16 h0 = __float2bfloat16(x);
            const float f0 = __bfloat162float(h0);
            const float r1 = x - f0;
            __hip_bfloat16 h1 = __float2bfloat16(r1);
            const float f1 = __bfloat162float(h1);
            const float r2 = r1 - f1;
            __hip_bfloat16 h2 = __float2bfloat16(r2);
            vh[j] = *(unsigned short*)&h0;
            vm[j] = *(unsigned short*)&h1;
            vl[j] = *(unsigned short*)&h2;
        }
        *(u16x8*)(outp + base0)        = vh;   // hi
        *(u16x8*)(outp + base0 + 1024) = vm;   // mid
        *(u16x8*)(outp + base0 + 2048) = vl;   // lo
    }
}

// ---------------------------------------------------------------------------
// K2 v18 = R16 + TWO COL-TILES PER STEP (structural ILP: 12 fragment loads
// issued together, then 2x12 MFMA chains; second tile's loads overlap first
// tile's MFMAs; 8 exposed-latency windows instead of 16). Phase A is
// barrier-free. MFMA chain order per col-tile identical to R16/R17 ->
// bit-identical scores (absmax stays exactly 4.119873e-3).
// ---------------------------------------------------------------------------
__global__ __launch_bounds__(512, 2)
void scores_topk(const unsigned short* __restrict__ qfrag,
                 const unsigned short* __restrict__ kfrag,
                 float* __restrict__ svals,
                 unsigned short* __restrict__ sidx, int* __restrict__ scnt)
{
    __shared__ float S[16][2052];   // 131328 B

    const int t    = threadIdx.x;
    const int lane = t & 63;
    const int wid  = t >> 6;                        // 0..7
    const int id   = blockIdx.x;                    // 0..4095
    const int bh   = ((id >> 10) << 3) | (id & 7);  // XCD-affine, bijective
    const int rowblk = (id >> 3) & 127;
    const int r0   = rowblk << 4;                   // block's 16 rows

    // A fragments: one coalesced 16B/lane load per fragment
    const bf16x8* qf = (const bf16x8*)qfrag
                     + (((size_t)bh * 128 + rowblk) * 6) * 64 + lane;
    bf16x8 afr[6];
#pragma unroll
    for (int f = 0; f < 6; ++f) afr[f] = qf[f * 64];

    const bf16x8* kf = (const bf16x8*)kfrag + ((size_t)bh * 128 * 6) * 64 + lane;

#define MCHAIN(ACC, B0, B1, B2, B3, B4, B5)                                    \
        ACC = __builtin_amdgcn_mfma_f32_16x16x32_bf16(afr[0], B0, ACC, 0, 0, 0); \
        ACC = __builtin_amdgcn_mfma_f32_16x16x32_bf16(afr[1], B1, ACC, 0, 0, 0); \
        ACC = __builtin_amdgcn_mfma_f32_16x16x32_bf16(afr[0], B2, ACC, 0, 0, 0); \
        ACC = __builtin_amdgcn_mfma_f32_16x16x32_bf16(afr[1], B3, ACC, 0, 0, 0); \
        ACC = __builtin_amdgcn_mfma_f32_16x16x32_bf16(afr[2], B0, ACC, 0, 0, 0); \
        ACC = __builtin_amdgcn_mfma_f32_16x16x32_bf16(afr[3], B1, ACC, 0, 0, 0); \
        ACC = __builtin_amdgcn_mfma_f32_16x16x32_bf16(afr[2], B2, ACC, 0, 0, 0); \
        ACC = __builtin_amdgcn_mfma_f32_16x16x32_bf16(afr[3], B3, ACC, 0, 0, 0); \
        ACC = __builtin_amdgcn_mfma_f32_16x16x32_bf16(afr[0], B4, ACC, 0, 0, 0); \
        ACC = __builtin_amdgcn_mfma_f32_16x16x32_bf16(afr[1], B5, ACC, 0, 0, 0); \
        ACC = __builtin_amdgcn_mfma_f32_16x16x32_bf16(afr[4], B0, ACC, 0, 0, 0); \
        ACC = __builtin_amdgcn_mfma_f32_16x16x32_bf16(afr[5], B1, ACC, 0, 0, 0);

#define STEP2(I)                                                               \
    {                                                                          \
        const int ct0 = (((I) << 1) << 3) + wid;                               \
        const int ct1 = ((((I) << 1) | 1) << 3) + wid;                         \
        const bf16x8* kb0 = kf + (size_t)ct0 * 384;                            \
        const bf16x8* kb1 = kf + (size_t)ct1 * 384;                            \
        bf16x8 b0 = kb0[0];   bf16x8 b1 = kb0[64];  bf16x8 b2 = kb0[128];      \
        bf16x8 b3 = kb0[192]; bf16x8 b4 = kb0[256]; bf16x8 b5 = kb0[320];      \
        bf16x8 c0 = kb1[0];   bf16x8 c1 = kb1[64];  bf16x8 c2 = kb1[128];      \
        bf16x8 c3 = kb1[192]; bf16x8 c4 = kb1[256]; bf16x8 c5 = kb1[320];      \
        f32x4 acc0 = {0.f, 0.f, 0.f, 0.f};                                     \
        MCHAIN(acc0, b0, b1, b2, b3, b4, b5)                                   \
        f32x4 acc1 = {0.f, 0.f, 0.f, 0.f};                                     \
        MCHAIN(acc1, c0, c1, c2, c3, c4, c5)                                   \
        const int rbase = (lane >> 4) << 2;                                    \
        const int col0  = (ct0 << 4) + (lane & 15);                            \
        const int col1  = (ct1 << 4) + (lane & 15);                            \
        S[rbase + 0][col0] = acc0[0] * 0.125f;                                 \
        S[rbase + 1][col0] = acc0[1] * 0.125f;                                 \
        S[rbase + 2][col0] = acc0[2] * 0.125f;                                 \
        S[rbase + 3][col0] = acc0[3] * 0.125f;                                 \
        S[rbase + 0][col1] = acc1[0] * 0.125f;                                 \
        S[rbase + 1][col1] = acc1[1] * 0.125f;                                 \
        S[rbase + 2][col1] = acc1[2] * 0.125f;                                 \
        S[rbase + 3][col1] = acc1[3] * 0.125f;                                 \
    }

    STEP2(0) STEP2(1) STEP2(2) STEP2(3)
    STEP2(4) STEP2(5) STEP2(6) STEP2(7)
#undef STEP2
#undef MCHAIN

    __syncthreads();

    // phase B: 2 rows/wave; exact 64th-largest via early-exit bisection
    const unsigned long long pre64 = (1ull << lane) - 1ull;

#define PHASEB(RQ)                                                             \
    {                                                                          \
        const int rr = (wid << 1) + (RQ);                                      \
        float    fv[32];                                                       \
        unsigned uv[32];                                                       \
        _Pragma("unroll")                                                      \
        for (int m = 0; m < 32; ++m) {                                         \
            const float x = S[rr][lane + (m << 6)];                            \
            fv[m] = x;                                                         \
            const unsigned bx = __float_as_uint(x);                            \
            uv[m] = bx ^ (unsigned)(((int)bx >> 31) | 0x80000000);             \
        }                                                                      \
        unsigned lo = 0;                                                       \
        _Pragma("unroll 1")                                                    \
        for (int bit = 31; bit >= 0; --bit) {                                  \
            const unsigned mid = lo | (1u << bit);                             \
            int c = 0;                                                         \
            _Pragma("unroll")                                                  \
            for (int m = 0; m < 32; ++m)                                       \
                c += __popcll(__ballot(uv[m] >= mid));                         \
            if (c >= 64) {                                                     \
                lo = mid;                                                      \
                if (c == 64) break;                                            \
            }                                                                  \
        }                                                                      \
        unsigned um = 0;                                                       \
        _Pragma("unroll")                                                      \
        for (int m = 0; m < 32; ++m) um = uv[m] > um ? uv[m] : um;             \
        _Pragma("unroll")                                                      \
        for (int off = 1; off < 64; off <<= 1) {                               \
            const unsigned o = (unsigned)__shfl_xor((int)um, off, 64);         \
            um = o > um ? o : um;                                              \
        }                                                                      \
        const unsigned mbm = (um & 0x80000000u) ? (um ^ 0x80000000u) : ~um;    \
        const float Mx = __uint_as_float(mbm);                                 \
        float zs = 0.f;                                                        \
        _Pragma("unroll")                                                      \
        for (int m = 0; m < 32; ++m) {                                         \
            const bool keep = uv[m] >= lo;                                     \
            const float ex = keep ? __expf(fv[m] - Mx) : 0.f;                  \
            fv[m] = ex;                                                        \
            zs += ex;                                                          \
        }                                                                      \
        _Pragma("unroll")                                                      \
        for (int off = 1; off < 64; off <<= 1) zs += __shfl_xor(zs, off, 64);  \
        const float zinv = 1.0f / zs;                                          \
        const size_t grow = (size_t)bh * 2048 + r0 + rr;                       \
        float* vd           = svals + grow * SLOTS;                            \
        unsigned short* idp = sidx  + grow * SLOTS;                            \
        int base = 0;                                                          \
        _Pragma("unroll")                                                      \
        for (int m = 0; m < 32; ++m) {                                         \
            const bool keep = uv[m] >= lo;                                     \
            unsigned long long ball = __ballot(keep);                          \
            if (keep) {                                                        \
                const int my = base + __popcll(ball & pre64);                  \
                if (my < SLOTS) {                                              \
                    vd[my]  = fv[m] * zinv;                                    \
                    idp[my] = (unsigned short)(lane + (m << 6));               \
                }                                                              \
            }                                                                  \
            base += __popcll(ball);                                            \
        }                                                                      \
        if (lane == 0) scnt[grow] = base < SLOTS ? base : SLOTS;               \
    }

    PHASEB(0)
    PHASEB(1)
#undef PHASEB
}

// ---------------------------------------------------------------------------
// K3: sparse attn application (unchanged: x8 unroll + XCD-affine).
// ---------------------------------------------------------------------------
__global__ __launch_bounds__(256)
void spmm(const float* __restrict__ svals, const unsigned short* __restrict__ sidx,
          const int* __restrict__ scnt, const float* __restrict__ qkv,
          const float* __restrict__ vin, float* __restrict__ vout,
          float* __restrict__ res, const float* __restrict__ alphas_raw, int order)
{
    const int lane = threadIdx.x & 63;
    const int id   = blockIdx.x;                      // 0..16383
    const int bh   = ((id & 7) << 2) | (id >> 12);    // XCD-affine, bijective
    const int nblk = (id >> 3) & 511;
    const int n    = (nblk << 2) + (threadIdx.x >> 6);
    const int gr   = (bh << 11) + n;
    const int b    = bh >> 3,  h = bh & 7;

    const float* vb;
    int stride;
    if (order == 0) { vb = qkv + (size_t)b * 2048 * 1536 + 1024 + (h << 6); stride = 1536; }
    else            { vb = vin + ((size_t)bh << 17);                        stride = 64;   }

    const int cnt = scnt[gr];
    const float* va          = svals + (size_t)gr * SLOTS;
    const unsigned short* ia = sidx  + (size_t)gr * SLOTS;

    float acc = 0.f;
    int j = 0;
    for (; j + 8 <= cnt; j += 8) {
        float a0 = va[j],     a1 = va[j + 1], a2 = va[j + 2], a3 = va[j + 3];
        float a4 = va[j + 4], a5 = va[j + 5], a6 = va[j + 6], a7 = va[j + 7];
        int   i0 = ia[j],     i1 = ia[j + 1], i2 = ia[j + 2], i3 = ia[j + 3];
        int   i4 = ia[j + 4], i5 = ia[j + 5], i6 = ia[j + 6], i7 = ia[j + 7];
        acc += a0 * vb[(size_t)i0 * stride + lane];
        acc += a1 * vb[(size_t)i1 * stride + lane];
        acc += a2 * vb[(size_t)i2 * stride + lane];
        acc += a3 * vb[(size_t)i3 * stride + lane];
        acc += a4 * vb[(size_t)i4 * stride + lane];
        acc += a5 * vb[(size_t)i5 * stride + lane];
        acc += a6 * vb[(size_t)i6 * stride + lane];
        acc += a7 * vb[(size_t)i7 * stride + lane];
    }
    for (; j < cnt; ++j) acc += va[j] * vb[(size_t)ia[j] * stride + lane];

    if (order < 2) vout[((size_t)gr << 6) + lane] = acc;

    float ar    = alphas_raw[(order << 3) + h];
    float alpha = ar * 0.5f * (1.0f + erff(ar * 0.70710678f));  // exact gelu
    size_t ro = ((size_t)b * 2048 + n) * 512 + (h << 6) + lane;
    float av  = alpha * acc;
    if (order == 0) res[ro] = av;
    else            res[ro] += av;
}

// ---------------------------------------------------------------------------
extern "C" void kernel_launch(void* const* d_in, const int* in_sizes, int n_in,
                              void* d_out, int out_size, void* d_ws, size_t ws_size,
                              hipStream_t stream)
{
    const float* x      = (const float*)d_in[0];
    const float* Wqkv   = (const float*)d_in[1];
    const float* bqkv   = (const float*)d_in[2];
    const float* Wout   = (const float*)d_in[3];
    const float* bout   = (const float*)d_in[4];
    const float* alphas = (const float*)d_in[5];
    float* out = (float*)d_out;

    // workspace layout (bytes)
    char* ws = (char*)d_ws;
    float*          qkvb  = (float*)ws;                       // 50331648
    float*          svals = (float*)(ws + 50331648);          // 20971520
    unsigned short* sidxp = (unsigned short*)(ws + 71303168); // 10485760
    int*            scntp = (int*)(ws + 81788928);            // 262144
    // v1/v2/resb region (50331648 B at +82051072) is time-shared:
    //  - during K1b/K2: qfrag (25165824) + kfrag (25165824)
    //  - during spmm/K4: v1, v2, resb (3 x 16777216)
    unsigned short* qfrag = (unsigned short*)(ws + 82051072);
    unsigned short* kfrag = (unsigned short*)(ws + 107216896);
    float*          v1    = (float*)(ws + 82051072);
    float*          v2    = (float*)(ws + 98828288);
    float*          resb  = (float*)(ws + 115605504);
    if (ws_size < 132382720) return;                          // need ~126 MB

    // K1: qkv = x @ Wqkv + bqkv
    sgemm_bias<<<dim3(1536 / 128, 8192 / 128), 256, 0, stream>>>(
        x, Wqkv, bqkv, qkvb, 8192, 1536, 512);

    // K1b: exact bf16x3 split of Q,K into fragment-packed layout (vectorized)
    qk_split<<<2048, 256, 0, stream>>>(qkvb, qfrag, kfrag);

    // K2: MFMA scores -> exact top-64(+ties) -> softmax -> sparse rows
    scores_topk<<<4096, 512, 0, stream>>>(qfrag, kfrag, svals, sidxp, scntp);

    // K3 x3: polynomial filter (sparse A applications) — overwrites q/kfrag
    spmm<<<16384, 256, 0, stream>>>(svals, sidxp, scntp, qkvb, nullptr, v1, resb, alphas, 0);
    spmm<<<16384, 256, 0, stream>>>(svals, sidxp, scntp, qkvb, v1, v2, resb, alphas, 1);
    spmm<<<16384, 256, 0, stream>>>(svals, sidxp, scntp, qkvb, v2, nullptr, resb, alphas, 2);

    // K4: out = res @ Wout + bout
    sgemm_bias<<<dim3(512 / 128, 8192 / 128), 256, 0, stream>>>(
        resb, Wout, bout, out, 8192, 512, 512);
}

// Round 19
// 803.444 us; speedup vs baseline: 1.5050x; 1.2126x over previous
//
#include <hip/hip_runtime.h>
#include <hip/hip_bf16.h>

// Problem constants: B=4, N=2048, DIM=512, H=8, DH=64, ORDER=3, TOPK=64, INNER=512
#define SLOTS 80   // sparse slots per row (64 + tie headroom)

typedef __bf16 bf16x8 __attribute__((ext_vector_type(8)));
typedef float  f32x4  __attribute__((ext_vector_type(4)));
typedef unsigned short u16x8 __attribute__((ext_vector_type(8)));

// ---------------------------------------------------------------------------
// K1/K4: fp32 tiled GEMM with bias (unchanged).
// ---------------------------------------------------------------------------
__global__ __launch_bounds__(256)
void sgemm_bias(const float* __restrict__ A, const float* __restrict__ Bm,
                const float* __restrict__ bias, float* __restrict__ C,
                int M, int N, int K)
{
    __shared__ float As[16][132];
    __shared__ float Bs[16][132];

    const int t  = threadIdx.x;
    const int tx = t & 15, ty = t >> 4;
    const int bm = blockIdx.y << 7, bn = blockIdx.x << 7;

    const int arow = t >> 2,  ak4 = (t & 3) << 2;
    const int bkr  = t >> 5,  bc4 = (t & 31) << 2;

    float4 pa[2], pb[2];
#pragma unroll
    for (int s = 0; s < 2; ++s) {
        pa[s] = *(const float4*)&A[(size_t)(bm + arow + (s << 6)) * K + ak4];
        pb[s] = *(const float4*)&Bm[(size_t)(bkr + (s << 3)) * N + bn + bc4];
    }

    float acc[8][8] = {};

    for (int k0 = 0; k0 < K; k0 += 16) {
        __syncthreads();
#pragma unroll
        for (int s = 0; s < 2; ++s) {
            const int ar = arow + (s << 6);
            As[ak4 + 0][ar] = pa[s].x;
            As[ak4 + 1][ar] = pa[s].y;
            As[ak4 + 2][ar] = pa[s].z;
            As[ak4 + 3][ar] = pa[s].w;
            *(float4*)&Bs[bkr + (s << 3)][bc4] = pb[s];
        }
        __syncthreads();
        if (k0 + 16 < K) {
#pragma unroll
            for (int s = 0; s < 2; ++s) {
                pa[s] = *(const float4*)&A[(size_t)(bm + arow + (s << 6)) * K + k0 + 16 + ak4];
                pb[s] = *(const float4*)&Bm[(size_t)(k0 + 16 + bkr + (s << 3)) * N + bn + bc4];
            }
        }
#pragma unroll
        for (int kk = 0; kk < 16; ++kk) {
            float4 a0 = *(const float4*)&As[kk][(ty << 3) + 0];
            float4 a1 = *(const float4*)&As[kk][(ty << 3) + 4];
            float4 b0 = *(const float4*)&Bs[kk][(tx << 2)];
            float4 b1 = *(const float4*)&Bs[kk][64 + (tx << 2)];
            float ar[8] = {a0.x, a0.y, a0.z, a0.w, a1.x, a1.y, a1.z, a1.w};
            float br[8] = {b0.x, b0.y, b0.z, b0.w, b1.x, b1.y, b1.z, b1.w};
#pragma unroll
            for (int i = 0; i < 8; ++i)
#pragma unroll
                for (int j = 0; j < 8; ++j)
                    acc[i][j] = fmaf(ar[i], br[j], acc[i][j]);
        }
    }

    float bb[8];
#pragma unroll
    for (int j = 0; j < 4; ++j) {
        bb[j]     = bias[bn + (tx << 2) + j];
        bb[j + 4] = bias[bn + 64 + (tx << 2) + j];
    }
#pragma unroll
    for (int i = 0; i < 8; ++i) {
        const size_t row = (size_t)(bm + (ty << 3) + i);
        float4 o0 = {acc[i][0] + bb[0], acc[i][1] + bb[1], acc[i][2] + bb[2], acc[i][3] + bb[3]};
        float4 o1 = {acc[i][4] + bb[4], acc[i][5] + bb[5], acc[i][6] + bb[6], acc[i][7] + bb[7]};
        *(float4*)&C[row * N + bn + (tx << 2)]      = o0;
        *(float4*)&C[row * N + bn + 64 + (tx << 2)] = o1;
    }
}

// ---------------------------------------------------------------------------
// K1b: exact bf16x3 split, vectorized (unchanged from R18).
// ---------------------------------------------------------------------------
__global__ __launch_bounds__(256)
void qk_split(const float* __restrict__ qkv, unsigned short* __restrict__ qfrag,
              unsigned short* __restrict__ kfrag)
{
    const int gid = blockIdx.x * 256 + threadIdx.x;   // 0 .. 524287
    const int dg = gid & 7;                            // d-group: d = dg*8+j
    const int h  = (gid >> 3) & 7;
    const int n  = (gid >> 6) & 2047;
    const int b  = gid >> 17;
    const int bh = (b << 3) + h;

    const size_t src = ((size_t)(b * 2048 + n)) * 1536 + (h << 6) + (dg << 3);

    const int tb = n >> 4;
    const int c  = n & 15;
    const int ks = dg >> 2;                 // d>>5
    const int ln = c | ((dg & 3) << 4);     // c | ((kk>>3)<<4)
    const size_t base0 = ((((size_t)bh * 128 + tb) * 6 + ks) * 64 + ln) * 8;

#pragma unroll
    for (int qk = 0; qk < 2; ++qk) {
        const float4 x0 = *(const float4*)&qkv[src + (qk ? 512 : 0)];
        const float4 x1 = *(const float4*)&qkv[src + (qk ? 512 : 0) + 4];
        unsigned short* outp = qk ? kfrag : qfrag;
        const float xs[8] = {x0.x, x0.y, x0.z, x0.w, x1.x, x1.y, x1.z, x1.w};
        u16x8 vh, vm, vl;
#pragma unroll
        for (int j = 0; j < 8; ++j) {
            const float x = xs[j];
            __hip_bfloat16 h0 = __float2bfloat16(x);
            const float f0 = __bfloat162float(h0);
            const float r1 = x - f0;
            __hip_bfloat16 h1 = __float2bfloat16(r1);
            const float f1 = __bfloat162float(h1);
            const float r2 = r1 - f1;
            __hip_bfloat16 h2 = __float2bfloat16(r2);
            vh[j] = *(unsigned short*)&h0;
            vm[j] = *(unsigned short*)&h1;
            vl[j] = *(unsigned short*)&h2;
        }
        *(u16x8*)(outp + base0)        = vh;   // hi
        *(u16x8*)(outp + base0 + 1024) = vm;   // mid
        *(u16x8*)(outp + base0 + 2048) = vl;   // lo
    }
}

// ---------------------------------------------------------------------------
// K2 v19: HALVED LDS via deferred half-C-fragments.
// Phase A (identical MFMA chain to R16-R18 -> bit-identical scores): per
// iter store acc[0],acc[1] (rows rbase+0,rbase+1 -> S slot 2*(lane>>4)+reg,
// 8 distinct rows) and DEFER acc[2],acc[3] in 32 literal-indexed registers.
// S[8][2052] = 64KB -> 2 blocks/CU (4 waves/SIMD, launch_bounds(512,4)).
// Schedule: phaseA | bar | PB(rows {0,1,4,5,8,9,12,13}) | bar | store
// deferred | bar | PB(rows +2). Same values, same per-row compaction ->
// absmax stays exactly 4.119873e-3.
// ---------------------------------------------------------------------------
__global__ __launch_bounds__(512, 4)
void scores_topk(const unsigned short* __restrict__ qfrag,
                 const unsigned short* __restrict__ kfrag,
                 float* __restrict__ svals,
                 unsigned short* __restrict__ sidx, int* __restrict__ scnt)
{
    __shared__ float S[8][2052];   // 65664 B

    const int t    = threadIdx.x;
    const int lane = t & 63;
    const int wid  = t >> 6;                        // 0..7
    const int id   = blockIdx.x;                    // 0..4095
    const int bh   = ((id >> 10) << 3) | (id & 7);  // XCD-affine, bijective
    const int rowblk = (id >> 3) & 127;
    const int r0   = rowblk << 4;                   // block's 16 rows

    // A fragments: one coalesced 16B/lane load per fragment
    const bf16x8* qf = (const bf16x8*)qfrag
                     + (((size_t)bh * 128 + rowblk) * 6) * 64 + lane;
    bf16x8 afr[6];
#pragma unroll
    for (int f = 0; f < 6; ++f) afr[f] = qf[f * 64];

    const bf16x8* kf = (const bf16x8*)kfrag + ((size_t)bh * 128 * 6) * 64 + lane;

    const int slot0 = (lane >> 4) << 1;             // S row-slot for acc[0]
    float def[32];                                  // deferred acc[2],acc[3]

#define STEP(I)                                                                \
    {                                                                          \
        const int ct = ((I) << 3) + wid;                                       \
        const bf16x8* kb = kf + (size_t)ct * 384;                              \
        bf16x8 b0 = kb[0];   bf16x8 b1 = kb[64];  bf16x8 b2 = kb[128];         \
        bf16x8 b3 = kb[192]; bf16x8 b4 = kb[256]; bf16x8 b5 = kb[320];         \
        f32x4 acc = {0.f, 0.f, 0.f, 0.f};                                      \
        acc = __builtin_amdgcn_mfma_f32_16x16x32_bf16(afr[0], b0, acc, 0, 0, 0); \
        acc = __builtin_amdgcn_mfma_f32_16x16x32_bf16(afr[1], b1, acc, 0, 0, 0); \
        acc = __builtin_amdgcn_mfma_f32_16x16x32_bf16(afr[0], b2, acc, 0, 0, 0); \
        acc = __builtin_amdgcn_mfma_f32_16x16x32_bf16(afr[1], b3, acc, 0, 0, 0); \
        acc = __builtin_amdgcn_mfma_f32_16x16x32_bf16(afr[2], b0, acc, 0, 0, 0); \
        acc = __builtin_amdgcn_mfma_f32_16x16x32_bf16(afr[3], b1, acc, 0, 0, 0); \
        acc = __builtin_amdgcn_mfma_f32_16x16x32_bf16(afr[2], b2, acc, 0, 0, 0); \
        acc = __builtin_amdgcn_mfma_f32_16x16x32_bf16(afr[3], b3, acc, 0, 0, 0); \
        acc = __builtin_amdgcn_mfma_f32_16x16x32_bf16(afr[0], b4, acc, 0, 0, 0); \
        acc = __builtin_amdgcn_mfma_f32_16x16x32_bf16(afr[1], b5, acc, 0, 0, 0); \
        acc = __builtin_amdgcn_mfma_f32_16x16x32_bf16(afr[4], b0, acc, 0, 0, 0); \
        acc = __builtin_amdgcn_mfma_f32_16x16x32_bf16(afr[5], b1, acc, 0, 0, 0); \
        const int col = (ct << 4) + (lane & 15);                               \
        S[slot0 + 0][col] = acc[0] * 0.125f;                                   \
        S[slot0 + 1][col] = acc[1] * 0.125f;                                   \
        def[2 * (I)]     = acc[2] * 0.125f;                                    \
        def[2 * (I) + 1] = acc[3] * 0.125f;                                    \
    }

    STEP(0)  STEP(1)  STEP(2)  STEP(3)
    STEP(4)  STEP(5)  STEP(6)  STEP(7)
    STEP(8)  STEP(9)  STEP(10) STEP(11)
    STEP(12) STEP(13) STEP(14) STEP(15)
#undef STEP

    __syncthreads();

    // phase B: wave wid processes S row-slot wid. Half-1 rows:
    // r = ((wid>>1)<<2) | (wid&1)  in {0,1,4,5,8,9,12,13}; half-2: r+2.
    const unsigned long long pre64 = (1ull << lane) - 1ull;

#define PHASEB(ROWOFF)                                                         \
    {                                                                          \
        const int rrow = (((wid >> 1) << 2) | (wid & 1)) + (ROWOFF);           \
        float    fv[32];                                                       \
        unsigned uv[32];                                                       \
        _Pragma("unroll")                                                      \
        for (int m = 0; m < 32; ++m) {                                         \
            const float x = S[wid][lane + (m << 6)];                           \
            fv[m] = x;                                                         \
            const unsigned bx = __float_as_uint(x);                            \
            uv[m] = bx ^ (unsigned)(((int)bx >> 31) | 0x80000000);             \
        }                                                                      \
        unsigned lo = 0;                                                       \
        _Pragma("unroll 1")                                                    \
        for (int bit = 31; bit >= 0; --bit) {                                  \
            const unsigned mid = lo | (1u << bit);                             \
            int c = 0;                                                         \
            _Pragma("unroll")                                                  \
            for (int m = 0; m < 32; ++m)                                       \
                c += __popcll(__ballot(uv[m] >= mid));                         \
            if (c >= 64) {                                                     \
                lo = mid;                                                      \
                if (c == 64) break;                                            \
            }                                                                  \
        }                                                                      \
        unsigned um = 0;                                                       \
        _Pragma("unroll")                                                      \
        for (int m = 0; m < 32; ++m) um = uv[m] > um ? uv[m] : um;             \
        _Pragma("unroll")                                                      \
        for (int off = 1; off < 64; off <<= 1) {                               \
            const unsigned o = (unsigned)__shfl_xor((int)um, off, 64);         \
            um = o > um ? o : um;                                              \
        }                                                                      \
        const unsigned mbm = (um & 0x80000000u) ? (um ^ 0x80000000u) : ~um;    \
        const float Mx = __uint_as_float(mbm);                                 \
        float zs = 0.f;                                                        \
        _Pragma("unroll")                                                      \
        for (int m = 0; m < 32; ++m) {                                         \
            const bool keep = uv[m] >= lo;                                     \
            const float ex = keep ? __expf(fv[m] - Mx) : 0.f;                  \
            fv[m] = ex;                                                        \
            zs += ex;                                                          \
        }                                                                      \
        _Pragma("unroll")                                                      \
        for (int off = 1; off < 64; off <<= 1) zs += __shfl_xor(zs, off, 64);  \
        const float zinv = 1.0f / zs;                                          \
        const size_t grow = (size_t)bh * 2048 + r0 + rrow;                     \
        float* vd           = svals + grow * SLOTS;                            \
        unsigned short* idp = sidx  + grow * SLOTS;                            \
        int base = 0;                                                          \
        _Pragma("unroll")                                                      \
        for (int m = 0; m < 32; ++m) {                                         \
            const bool keep = uv[m] >= lo;                                     \
            unsigned long long ball = __ballot(keep);                          \
            if (keep) {                                                        \
                const int my = base + __popcll(ball & pre64);                  \
                if (my < SLOTS) {                                              \
                    vd[my]  = fv[m] * zinv;                                    \
                    idp[my] = (unsigned short)(lane + (m << 6));               \
                }                                                              \
            }                                                                  \
            base += __popcll(ball);                                            \
        }                                                                      \
        if (lane == 0) scnt[grow] = base < SLOTS ? base : SLOTS;               \
    }

    PHASEB(0)

    __syncthreads();

    // store deferred scores (rows rbase+2, rbase+3 -> same slot mapping)
#pragma unroll
    for (int I = 0; I < 16; ++I) {
        const int col = (((I << 3) + wid) << 4) + (lane & 15);
        S[slot0 + 0][col] = def[2 * I];
        S[slot0 + 1][col] = def[2 * I + 1];
    }
    __syncthreads();

    PHASEB(2)
#undef PHASEB
}

// ---------------------------------------------------------------------------
// K3: sparse attn application (unchanged: x8 unroll + XCD-affine).
// ---------------------------------------------------------------------------
__global__ __launch_bounds__(256)
void spmm(const float* __restrict__ svals, const unsigned short* __restrict__ sidx,
          const int* __restrict__ scnt, const float* __restrict__ qkv,
          const float* __restrict__ vin, float* __restrict__ vout,
          float* __restrict__ res, const float* __restrict__ alphas_raw, int order)
{
    const int lane = threadIdx.x & 63;
    const int id   = blockIdx.x;                      // 0..16383
    const int bh   = ((id & 7) << 2) | (id >> 12);    // XCD-affine, bijective
    const int nblk = (id >> 3) & 511;
    const int n    = (nblk << 2) + (threadIdx.x >> 6);
    const int gr   = (bh << 11) + n;
    const int b    = bh >> 3,  h = bh & 7;

    const float* vb;
    int stride;
    if (order == 0) { vb = qkv + (size_t)b * 2048 * 1536 + 1024 + (h << 6); stride = 1536; }
    else            { vb = vin + ((size_t)bh << 17);                        stride = 64;   }

    const int cnt = scnt[gr];
    const float* va          = svals + (size_t)gr * SLOTS;
    const unsigned short* ia = sidx  + (size_t)gr * SLOTS;

    float acc = 0.f;
    int j = 0;
    for (; j + 8 <= cnt; j += 8) {
        float a0 = va[j],     a1 = va[j + 1], a2 = va[j + 2], a3 = va[j + 3];
        float a4 = va[j + 4], a5 = va[j + 5], a6 = va[j + 6], a7 = va[j + 7];
        int   i0 = ia[j],     i1 = ia[j + 1], i2 = ia[j + 2], i3 = ia[j + 3];
        int   i4 = ia[j + 4], i5 = ia[j + 5], i6 = ia[j + 6], i7 = ia[j + 7];
        acc += a0 * vb[(size_t)i0 * stride + lane];
        acc += a1 * vb[(size_t)i1 * stride + lane];
        acc += a2 * vb[(size_t)i2 * stride + lane];
        acc += a3 * vb[(size_t)i3 * stride + lane];
        acc += a4 * vb[(size_t)i4 * stride + lane];
        acc += a5 * vb[(size_t)i5 * stride + lane];
        acc += a6 * vb[(size_t)i6 * stride + lane];
        acc += a7 * vb[(size_t)i7 * stride + lane];
    }
    for (; j < cnt; ++j) acc += va[j] * vb[(size_t)ia[j] * stride + lane];

    if (order < 2) vout[((size_t)gr << 6) + lane] = acc;

    float ar    = alphas_raw[(order << 3) + h];
    float alpha = ar * 0.5f * (1.0f + erff(ar * 0.70710678f));  // exact gelu
    size_t ro = ((size_t)b * 2048 + n) * 512 + (h << 6) + lane;
    float av  = alpha * acc;
    if (order == 0) res[ro] = av;
    else            res[ro] += av;
}

// ---------------------------------------------------------------------------
extern "C" void kernel_launch(void* const* d_in, const int* in_sizes, int n_in,
                              void* d_out, int out_size, void* d_ws, size_t ws_size,
                              hipStream_t stream)
{
    const float* x      = (const float*)d_in[0];
    const float* Wqkv   = (const float*)d_in[1];
    const float* bqkv   = (const float*)d_in[2];
    const float* Wout   = (const float*)d_in[3];
    const float* bout   = (const float*)d_in[4];
    const float* alphas = (const float*)d_in[5];
    float* out = (float*)d_out;

    // workspace layout (bytes)
    char* ws = (char*)d_ws;
    float*          qkvb  = (float*)ws;                       // 50331648
    float*          svals = (float*)(ws + 50331648);          // 20971520
    unsigned short* sidxp = (unsigned short*)(ws + 71303168); // 10485760
    int*            scntp = (int*)(ws + 81788928);            // 262144
    // v1/v2/resb region is time-shared with qfrag/kfrag (as R15-R18)
    unsigned short* qfrag = (unsigned short*)(ws + 82051072);
    unsigned short* kfrag = (unsigned short*)(ws + 107216896);
    float*          v1    = (float*)(ws + 82051072);
    float*          v2    = (float*)(ws + 98828288);
    float*          resb  = (float*)(ws + 115605504);
    if (ws_size < 132382720) return;                          // need ~126 MB

    // K1: qkv = x @ Wqkv + bqkv
    sgemm_bias<<<dim3(1536 / 128, 8192 / 128), 256, 0, stream>>>(
        x, Wqkv, bqkv, qkvb, 8192, 1536, 512);

    // K1b: exact bf16x3 split of Q,K into fragment-packed layout (vectorized)
    qk_split<<<2048, 256, 0, stream>>>(qkvb, qfrag, kfrag);

    // K2: MFMA scores -> exact top-64(+ties) -> softmax -> sparse rows
    scores_topk<<<4096, 512, 0, stream>>>(qfrag, kfrag, svals, sidxp, scntp);

    // K3 x3: polynomial filter (sparse A applications) — overwrites q/kfrag
    spmm<<<16384, 256, 0, stream>>>(svals, sidxp, scntp, qkvb, nullptr, v1, resb, alphas, 0);
    spmm<<<16384, 256, 0, stream>>>(svals, sidxp, scntp, qkvb, v1, v2, resb, alphas, 1);
    spmm<<<16384, 256, 0, stream>>>(svals, sidxp, scntp, qkvb, v2, nullptr, resb, alphas, 2);

    // K4: out = res @ Wout + bout
    sgemm_bias<<<dim3(512 / 128, 8192 / 128), 256, 0, stream>>>(
        resb, Wout, bout, out, 8192, 512, 512);
}